// Round 1
// baseline (721.104 us; speedup 1.0000x reference)
//
#include <hip/hip_runtime.h>

#define T_STEPS 512
#define BATCH   256

typedef _Float16 f16;
typedef unsigned long long u64;
typedef unsigned int u32;
typedef __attribute__((ext_vector_type(8))) _Float16 f16x8;
typedef __attribute__((ext_vector_type(4))) _Float16 f16x4;
typedef __attribute__((ext_vector_type(4))) float    f32x4;

#define L2E 1.44269504088896340736f

__device__ __forceinline__ float rcp_f(float x)  { return __builtin_amdgcn_rcpf(x); }
__device__ __forceinline__ float exp2_f(float x) { return __builtin_amdgcn_exp2f(x); }

// tanh in exp2 domain: tanh(x) = 1 - 2/(exp2(2*log2e*x)+1)
__device__ __forceinline__ float tanh_n(float x) {
    return fmaf(-2.0f, rcp_f(1.0f + exp2_f(2.0f * L2E * x)), 1.0f);
}
// tanh on 4 packed f16 (bottleneck tanh, applied on L2's panel store)
__device__ __forceinline__ u64 tanh4_f16(u64 v) {
    f16x4 h = __builtin_bit_cast(f16x4, v);
    f16x4 r;
#pragma unroll
    for (int i = 0; i < 4; ++i) r[i] = (f16)tanh_n((float)h[i]);
    return __builtin_bit_cast(u64, r);
}

// Per-step barrier: LDS visibility only (global ops NOT drained).
__device__ __forceinline__ void barrier_lgkm() {
    asm volatile("s_waitcnt lgkmcnt(0)\n\ts_barrier" ::: "memory");
}
// Signal-point barrier: drain all VMEM so panels are globally visible.
__device__ __forceinline__ void barrier_drain() {
    asm volatile("s_waitcnt vmcnt(0) lgkmcnt(0)\n\ts_barrier" ::: "memory");
}

// Agent-scope relaxed atomics -> sc1 ops, coherent at L3 across XCDs.
__device__ __forceinline__ int  flag_load(const int* p) {
    return __hip_atomic_load(p, __ATOMIC_RELAXED, __HIP_MEMORY_SCOPE_AGENT);
}
__device__ __forceinline__ void flag_store(int* p, int v) {
    __hip_atomic_store(p, v, __ATOMIC_RELAXED, __HIP_MEMORY_SCOPE_AGENT);
}
__device__ __forceinline__ u64  panel_load(const u64* p) {
    return __hip_atomic_load(p, __ATOMIC_RELAXED, __HIP_MEMORY_SCOPE_AGENT);
}
__device__ __forceinline__ void panel_store(u64* p, u64 v) {
    __hip_atomic_store(p, v, __ATOMIC_RELAXED, __HIP_MEMORY_SCOPE_AGENT);
}

__device__ __forceinline__ void cvt_store4(f16* dst, f32x4 v) {
    f16x4 h;
    h[0] = (f16)v[0]; h[1] = (f16)v[1]; h[2] = (f16)v[2]; h[3] = (f16)v[3];
    *reinterpret_cast<f16x4*>(dst) = h;
}

// Persistent per-wave LSTM state for one 16-col u-tile (all 4 gates).
// Weights scaled by log2e (gates i,f,o) and 2*log2e (gate g) at load time;
// cell state kept in the 2*log2e domain (verified structure from prior rounds).
template <int IN_DIM, int H>
struct Lstm {
    static constexpr int KTX = IN_DIM / 32, KTH = H / 32, KT = KTX + KTH;
    f16x8 bw[4][KT];
    float bias[4];
    float cst[4];
    int u, q;

    __device__ __forceinline__ void init(const float* __restrict__ w_ih,
                                         const float* __restrict__ w_hh,
                                         const float* __restrict__ b_ih,
                                         const float* __restrict__ b_hh,
                                         int unit, int lane) {
        q = lane >> 4;
        u = unit * 16 + (lane & 15);
#pragma unroll
        for (int g = 0; g < 4; ++g) {
            const float sc = (g == 2) ? 2.0f * L2E : L2E;
            const int row = g * H + u;
#pragma unroll
            for (int kt = 0; kt < KTX; ++kt) {
                const float* p = w_ih + (size_t)row * IN_DIM + kt * 32 + q * 8;
                f16x8 v;
#pragma unroll
                for (int j = 0; j < 8; ++j) v[j] = (f16)(p[j] * sc);
                bw[g][kt] = v;
            }
#pragma unroll
            for (int kt = 0; kt < KTH; ++kt) {
                const float* p = w_hh + (size_t)row * H + kt * 32 + q * 8;
                f16x8 v;
#pragma unroll
                for (int j = 0; j < 8; ++j) v[j] = (f16)(p[j] * sc);
                bw[g][KTX + kt] = v;
            }
            bias[g] = (b_ih[g * H + u] + b_hh[g * H + u]) * sc;
            cst[g] = 0.f;
        }
    }

    // in_row  = &input[ip][col][0]  (f16, row stride = input pad width)
    // rec_row = &own_h[wp^1][col][0]
    // hdst    = &own_h[wp][0][0] ; writes hdst[(4q+r)*hp + u]
    __device__ __forceinline__ void step(const f16* in_row, const f16* rec_row,
                                         f16* hdst, int hp, float hold[4]) {
        f16x8 a[KT];
#pragma unroll
        for (int kt = 0; kt < KTX; ++kt)
            a[kt] = *reinterpret_cast<const f16x8*>(in_row + kt * 32 + q * 8);
#pragma unroll
        for (int kt = 0; kt < KTH; ++kt)
            a[KTX + kt] = *reinterpret_cast<const f16x8*>(rec_row + kt * 32 + q * 8);
        f32x4 acc[4];
#pragma unroll
        for (int g = 0; g < 4; ++g)
            acc[g] = (f32x4){bias[g], bias[g], bias[g], bias[g]};
#pragma unroll
        for (int kt = 0; kt < KT; ++kt)
#pragma unroll
            for (int g = 0; g < 4; ++g)
                acc[g] = __builtin_amdgcn_mfma_f32_16x16x32_f16(a[kt], bw[g][kt], acc[g], 0, 0, 0);
#pragma unroll
        for (int r = 0; r < 4; ++r) {
            const float yi = acc[0][r], yf = acc[1][r], yg = acc[2][r], yo = acc[3][r];
            const float si = rcp_f(1.0f + exp2_f(-yi));
            const float sf = rcp_f(1.0f + exp2_f(-yf));
            const float dg = rcp_f(1.0f + exp2_f(yg));            // 1/(e^{2g}+1)
            const float tgp = fmaf(dg, -4.0f * L2E, 2.0f * L2E);  // 2*log2e*tanh(g)
            cst[r] = fmaf(sf, cst[r], si * tgp);                  // c' = 2*log2e*c
            const float dc = rcp_f(1.0f + exp2_f(cst[r]));
            const float th = fmaf(-2.0f, dc, 1.0f);               // tanh(c)
            const float so = rcp_f(1.0f + exp2_f(-yo));
            const float h = so * th;
            hdst[(4 * q + r) * hp + u] = (f16)h;
            hold[r] = h;
        }
    }
};

// Pair-fused pipeline:
//   blocks 0..15  (A): L1 (64->128, waves 0-7) + L2 (128->32, waves 8-9) +
//                      X-stagers (waves 10-11). L1->L2 handoff in LDS, 1-step skew.
//                      L2 publishes tanh'd 32-wide panels to global + flag.
//   blocks 16..31 (B): L3 (32->128, waves 0-7; wave 0 stages h2 panels) +
//                      L4 (128->64, waves 8-11, fp32 out). L3->L4 handoff in LDS.
// At global step s: L1 computes t=s, L2 t=s-1 (block A); L3 t=s, L4 t=s-1 (block B).
// Parity rule: layer writes h(t) into own buffer parity t&1; reads recurrence at
// (t&1)^1; reads its input panel at t&1 (producer wrote it one step earlier).
__global__ __launch_bounds__(768, 3)
void lstm_fused(const float* __restrict__ X,
                const float* __restrict__ w1_ih, const float* __restrict__ w1_hh,
                const float* __restrict__ b1_ih, const float* __restrict__ b1_hh,
                const float* __restrict__ w2_ih, const float* __restrict__ w2_hh,
                const float* __restrict__ b2_ih, const float* __restrict__ b2_hh,
                const float* __restrict__ w3_ih, const float* __restrict__ w3_hh,
                const float* __restrict__ b3_ih, const float* __restrict__ b3_hh,
                const float* __restrict__ w4_ih, const float* __restrict__ w4_hh,
                const float* __restrict__ b4_ih, const float* __restrict__ b4_hh,
                f16* __restrict__ h2t, int* __restrict__ flags,
                float* __restrict__ out)
{
    __shared__ __attribute__((aligned(16))) char sm[16384];
    const int b = blockIdx.x, tid = threadIdx.x;
    const int wave = tid >> 6, lane = tid & 63;
    const int col = lane & 15;

    if (b < 16) {
        // ================= block A: L1 + L2 =================
        const int g = b, bblk = g * 16;
        int* out_flag = flags + g;
        constexpr int XP1 = 72, HP1 = 136, HP2 = 40;            // padded row widths
        constexpr int XS_P = 16 * XP1, H1_P = 16 * HP1, H2_P = 16 * HP2;
        f16* xs  = (f16*)sm;                 // [2][16][72]   4608 B
        f16* h1  = (f16*)(sm + 4608);        // [2][16][136]  8704 B
        f16* h2r = (f16*)(sm + 13312);       // [2][16][40]   2560 B (raw h2, recurrence)

        // zero h1 + h2r (contiguous region)
        for (int i = tid; i < (2 * H1_P + 2 * H2_P) / 2; i += 768)
            ((u32*)h1)[i] = 0u;

        // stager setup (waves 10-11): 2 f32x4 chunks each, 2-step-ahead prefetch
        const float* xg0 = nullptr; const float* xg1 = nullptr;
        f16* xl0 = nullptr; f16* xl1 = nullptr;
        f32x4 hv0{}, hv1{};
        if (wave >= 10) {
            const int c0 = tid - 640, c1 = c0 + 128;
            const int r0 = c0 >> 4, o0 = (c0 & 15) * 4;
            const int r1 = c1 >> 4, o1 = (c1 & 15) * 4;
            xg0 = X + (size_t)(bblk + r0) * 64 + o0;
            xg1 = X + (size_t)(bblk + r1) * 64 + o1;
            xl0 = xs + r0 * XP1 + o0;
            xl1 = xs + r1 * XP1 + o1;
            // x(0) -> xs[0]
            f32x4 v0 = *(const f32x4*)xg0, v1 = *(const f32x4*)xg1;
            cvt_store4(xl0, v0); cvt_store4(xl1, v1);
            xg0 += (size_t)BATCH * 64; xg1 += (size_t)BATCH * 64;
            // issue x(1), held in regs across the first step
            hv0 = *(const f32x4*)xg0; hv1 = *(const f32x4*)xg1;
            xg0 += (size_t)BATCH * 64; xg1 += (size_t)BATCH * 64;
        }
        barrier_lgkm();   // pre-loop barrier (zeroes + x(0) visible)

        if (wave < 8) {
            // ---- L1: 64 -> 128, t = s ----
            Lstm<64, 128> L;
            L.init(w1_ih, w1_hh, b1_ih, b1_hh, wave, lane);
            float hd[4];
            const f16* in0 = xs + col * XP1;
            const f16* in1 = xs + XS_P + col * XP1;
            const f16* rc0 = h1 + col * HP1;
            const f16* rc1 = h1 + H1_P + col * HP1;
            f16* d0 = h1;
            f16* d1 = h1 + H1_P;
            for (int ss = 0; ss < 512; ss += 2) {
                L.step(in0, rc1, d0, HP1, hd);   // s=ss   (wp=0)
                barrier_lgkm();
                L.step(in1, rc0, d1, HP1, hd);   // s=ss+1 (wp=1)
                barrier_lgkm();
            }
            barrier_lgkm();   // tail s=512 (inactive)
            barrier_lgkm();   // post (final panel/flag sync)
        } else if (wave < 10) {
            // ---- L2: 128 -> 32, t2 = s-1; tanh'd panel -> global ----
            Lstm<128, 32> L;
            L.init(w2_ih, w2_hh, b2_ih, b2_hh, wave - 8, lane);
            float hd[4];
            const int t2id = tid - 512, orow = t2id >> 3, ooff = t2id & 7;
            u64* opg = (u64*)(h2t + (size_t)(bblk + orow) * 32) + ooff;
            const f16* in0 = h1 + col * HP1;               // ip == wp for delay-1 input
            const f16* in1 = h1 + H1_P + col * HP1;
            const f16* rc0 = h2r + col * HP2;
            const f16* rc1 = h2r + H2_P + col * HP2;
            f16* d0 = h2r;
            f16* d1 = h2r + H2_P;
            const f16* ol0 = h2r + orow * HP2 + ooff * 4;          // panel src parity 0
            const f16* ol1 = h2r + H2_P + orow * HP2 + ooff * 4;   // panel src parity 1
            for (int ss = 0; ss < 512; ss += 2) {
                // subA: s=ss, t2=ss-1 (odd, wp=1); active iff ss>=2
                if (ss >= 2) {
                    panel_store(opg, tanh4_f16(*(const u64*)ol0));  // panel t2-1 (even)
                    opg += (size_t)BATCH * 32 / 4;
                    L.step(in1, rc0, d1, HP2, hd);
                }
                if (ss >= 4 && (ss & 3) == 0) barrier_drain(); else barrier_lgkm();
                // subB: s=ss+1, t2=ss (even, wp=0)
                if (ss >= 4 && (ss & 3) == 0 && t2id == 0)
                    flag_store(out_flag, ss - 1);   // panels 0..ss-2 visible
                if (ss >= 2) {
                    panel_store(opg, tanh4_f16(*(const u64*)ol1));  // panel t2-1 (odd)
                    opg += (size_t)BATCH * 32 / 4;
                }
                L.step(in0, rc1, d0, HP2, hd);
                barrier_lgkm();
            }
            // tail s=512: t2=511 (wp=1); store panel 510
            panel_store(opg, tanh4_f16(*(const u64*)ol0));
            opg += (size_t)BATCH * 32 / 4;
            L.step(in1, rc0, d1, HP2, hd);
            barrier_lgkm();
            // post: final panel 511, drain both L2 waves, publish final flag
            panel_store(opg, tanh4_f16(*(const u64*)ol1));
            barrier_drain();
            if (t2id == 0) flag_store(out_flag, T_STEPS + 8);
        } else {
            // ---- X stagers: commit x(s+1) (held), issue x(s+2) ----
            for (int ss = 0; ss < 512; ss += 2) {
                // s=ss: commit x(ss+1) -> xs[1]
                cvt_store4(xl0 + XS_P, hv0); cvt_store4(xl1 + XS_P, hv1);
                if (ss + 2 < 512) {
                    hv0 = *(const f32x4*)xg0; hv1 = *(const f32x4*)xg1;
                    xg0 += (size_t)BATCH * 64; xg1 += (size_t)BATCH * 64;
                }
                barrier_lgkm();
                // s=ss+1: commit x(ss+2) -> xs[0]
                if (ss + 2 < 512) { cvt_store4(xl0, hv0); cvt_store4(xl1, hv1); }
                if (ss + 3 < 512) {
                    hv0 = *(const f32x4*)xg0; hv1 = *(const f32x4*)xg1;
                    xg0 += (size_t)BATCH * 64; xg1 += (size_t)BATCH * 64;
                }
                barrier_lgkm();
            }
            barrier_lgkm();
            barrier_lgkm();
        }
    } else {
        // ================= block B: L3 + L4 =================
        const int g = b - 16, bblk = g * 16;
        const int* in_flag = flags + g;
        constexpr int XP3 = 40, HP3 = 136, HP4 = 72;
        constexpr int X3_P = 16 * XP3, H3_P = 16 * HP3, H4_P = 16 * HP4;
        f16* xs3 = (f16*)sm;                 // [2][16][40]   2560 B
        f16* h3  = (f16*)(sm + 2560);        // [2][16][136]  8704 B
        f16* h4  = (f16*)(sm + 11264);       // [2][16][72]   4608 B

        for (int i = tid; i < (2 * H3_P + 2 * H4_P) / 2; i += 768)
            ((u32*)h3)[i] = 0u;

        // stager = wave 0: one f16x8 chunk each (64 chunks), 2-step-ahead
        const char* sgp = nullptr; f16* slp = nullptr;
        u64 ha = 0, hb = 0;
        int seen = 0;
        if (wave == 0) {
            const int r_ = tid >> 2, o_ = (tid & 3) * 8;
            sgp = (const char*)h2t + ((size_t)(bblk + r_) * 32 + o_) * 2;
            slp = xs3 + r_ * XP3 + o_;
            do { seen = flag_load(in_flag); } while (seen < 1);
            u64 pk[2];
            pk[0] = panel_load((const u64*)sgp);
            pk[1] = panel_load((const u64*)sgp + 1);
            sgp += (size_t)BATCH * 64;
            *reinterpret_cast<f16x8*>(slp) = *reinterpret_cast<const f16x8*>(pk);  // x(0)->xs3[0]
            while (seen < 2) seen = flag_load(in_flag);
            ha = panel_load((const u64*)sgp);   // issue x(1), held
            hb = panel_load((const u64*)sgp + 1);
            sgp += (size_t)BATCH * 64;
        }
        barrier_lgkm();

        if (wave < 8) {
            // ---- L3: 32 -> 128, t = s; wave 0 also stages h2 panels ----
            Lstm<32, 128> L;
            L.init(w3_ih, w3_hh, b3_ih, b3_hh, wave, lane);
            float hd[4];
            const f16* in0 = xs3 + col * XP3;
            const f16* in1 = xs3 + X3_P + col * XP3;
            const f16* rc0 = h3 + col * HP3;
            const f16* rc1 = h3 + H3_P + col * HP3;
            f16* d0 = h3;
            f16* d1 = h3 + H3_P;
            for (int ss = 0; ss < 512; ss += 2) {
                // s=ss (wp=0): commit x(ss+1)->xs3[1]; poll+issue x(ss+2)
                if (wave == 0) {
                    u64 pk[2] = {ha, hb};
                    *reinterpret_cast<f16x8*>(slp + X3_P) = *reinterpret_cast<const f16x8*>(pk);
                    if (ss + 2 < 512) {
                        if (seen < ss + 3) { do { seen = flag_load(in_flag); } while (seen < ss + 3); }
                        ha = panel_load((const u64*)sgp);
                        hb = panel_load((const u64*)sgp + 1);
                        sgp += (size_t)BATCH * 64;
                    }
                }
                L.step(in0, rc1, d0, HP3, hd);
                barrier_lgkm();
                // s=ss+1 (wp=1): commit x(ss+2)->xs3[0]; poll+issue x(ss+3)
                if (wave == 0) {
                    if (ss + 2 < 512) {
                        u64 pk[2] = {ha, hb};
                        *reinterpret_cast<f16x8*>(slp) = *reinterpret_cast<const f16x8*>(pk);
                    }
                    if (ss + 3 < 512) {
                        if (seen < ss + 4) { do { seen = flag_load(in_flag); } while (seen < ss + 4); }
                        ha = panel_load((const u64*)sgp);
                        hb = panel_load((const u64*)sgp + 1);
                        sgp += (size_t)BATCH * 64;
                    }
                }
                L.step(in1, rc0, d1, HP3, hd);
                barrier_lgkm();
            }
            barrier_lgkm();   // tail s=512 (inactive)
        } else {
            // ---- L4: 128 -> 64, t4 = s-1, fp32 delayed out-writes ----
            Lstm<128, 64> L;
            L.init(w4_ih, w4_hh, b4_ih, b4_hh, wave - 8, lane);
            float hold[4] = {0.f, 0.f, 0.f, 0.f};
            const int q4 = lane >> 4;
            const int u4 = (wave - 8) * 16 + col;
            float* outp = out + ((size_t)bblk + 4 * q4) * 64 + u4;
            const f16* in0 = h3 + col * HP3;
            const f16* in1 = h3 + H3_P + col * HP3;
            const f16* rc0 = h4 + col * HP4;
            const f16* rc1 = h4 + H4_P + col * HP4;
            f16* d0 = h4;
            f16* d1 = h4 + H4_P;
            for (int ss = 0; ss < 512; ss += 2) {
                // subA: s=ss, t4=ss-1 (odd, wp=1); active iff ss>=2
                if (ss >= 2) {
#pragma unroll
                    for (int r = 0; r < 4; ++r) outp[r * 64] = hold[r];  // out(t4-1)
                    outp += (size_t)BATCH * 64;
                    L.step(in1, rc0, d1, HP4, hold);
                }
                barrier_lgkm();
                // subB: s=ss+1, t4=ss (even, wp=0)
                if (ss >= 2) {
#pragma unroll
                    for (int r = 0; r < 4; ++r) outp[r * 64] = hold[r];
                    outp += (size_t)BATCH * 64;
                }
                L.step(in0, rc1, d0, HP4, hold);
                barrier_lgkm();
            }
            // tail s=512: t4=511 (wp=1)
#pragma unroll
            for (int r = 0; r < 4; ++r) outp[r * 64] = hold[r];   // out(510)
            outp += (size_t)BATCH * 64;
            L.step(in1, rc0, d1, HP4, hold);
            barrier_lgkm();
            // epilogue: out(511)
#pragma unroll
            for (int r = 0; r < 4; ++r) outp[r * 64] = hold[r];
        }
    }
}

extern "C" void kernel_launch(void* const* d_in, const int* in_sizes, int n_in,
                              void* d_out, int out_size, void* d_ws, size_t ws_size,
                              hipStream_t stream) {
    const float* X     = (const float*)d_in[0];
    const float* w1_ih = (const float*)d_in[1];
    const float* w1_hh = (const float*)d_in[2];
    const float* b1_ih = (const float*)d_in[3];
    const float* b1_hh = (const float*)d_in[4];
    const float* w2_ih = (const float*)d_in[5];
    const float* w2_hh = (const float*)d_in[6];
    const float* b2_ih = (const float*)d_in[7];
    const float* b2_hh = (const float*)d_in[8];
    const float* w3_ih = (const float*)d_in[9];
    const float* w3_hh = (const float*)d_in[10];
    const float* b3_ih = (const float*)d_in[11];
    const float* b3_hh = (const float*)d_in[12];
    const float* w4_ih = (const float*)d_in[13];
    const float* w4_hh = (const float*)d_in[14];
    const float* b4_ih = (const float*)d_in[15];
    const float* b4_hh = (const float*)d_in[16];

    float* out = (float*)d_out;

    // ws: flags[16] ints (poison 0xAAAAAAAA < 0 => "not ready"), then the one
    // remaining inter-block panel: h2t = tanh(h2), f16 [T,B,32] (8 MB).
    int* flags = (int*)d_ws;
    f16* h2t = (f16*)((char*)d_ws + 256);

    lstm_fused<<<32, 768, 0, stream>>>(X,
        w1_ih, w1_hh, b1_ih, b1_hh, w2_ih, w2_hh, b2_ih, b2_hh,
        w3_ih, w3_hh, b3_ih, b3_hh, w4_ih, w4_hh, b4_ih, b4_hh,
        h2t, flags, out);
}

// Round 2
// 695.757 us; speedup vs baseline: 1.0364x; 1.0364x over previous
//
#include <hip/hip_runtime.h>

#define T_STEPS 512
#define BATCH   256

typedef _Float16 f16;
typedef unsigned long long u64;
typedef unsigned int u32;
typedef __attribute__((ext_vector_type(8))) _Float16 f16x8;
typedef __attribute__((ext_vector_type(4))) _Float16 f16x4;
typedef __attribute__((ext_vector_type(4))) float    f32x4;

#define L2E 1.44269504088896340736f

__device__ __forceinline__ float rcp_f(float x)  { return __builtin_amdgcn_rcpf(x); }
__device__ __forceinline__ float exp2_f(float x) { return __builtin_amdgcn_exp2f(x); }

// tanh in exp2 domain: tanh(x) = 1 - 2/(exp2(2*log2e*x)+1)
__device__ __forceinline__ float tanh_n(float x) {
    return fmaf(-2.0f, rcp_f(1.0f + exp2_f(2.0f * L2E * x)), 1.0f);
}
// tanh on 4 packed f16 (bottleneck tanh, applied on L2's panel store)
__device__ __forceinline__ u64 tanh4_f16(u64 v) {
    f16x4 h = __builtin_bit_cast(f16x4, v);
    f16x4 r;
#pragma unroll
    for (int i = 0; i < 4; ++i) r[i] = (f16)tanh_n((float)h[i]);
    return __builtin_bit_cast(u64, r);
}

// Per-step barrier: LDS visibility only (global ops NOT drained).
__device__ __forceinline__ void barrier_lgkm() {
    asm volatile("s_waitcnt lgkmcnt(0)\n\ts_barrier" ::: "memory");
}
// Signal-point barrier: drain all VMEM so panels are globally visible.
__device__ __forceinline__ void barrier_drain() {
    asm volatile("s_waitcnt vmcnt(0) lgkmcnt(0)\n\ts_barrier" ::: "memory");
}
// Counted drain: leave the N newest vmem ops in flight (per-wave, in-order
// retirement). Used so the drain never waits on the store just issued.
__device__ __forceinline__ void wait_vm2() {
    asm volatile("s_waitcnt vmcnt(2)" ::: "memory");
}

// Agent-scope relaxed atomics -> sc1 ops, coherent at L3 across XCDs.
__device__ __forceinline__ int  flag_load(const int* p) {
    return __hip_atomic_load(p, __ATOMIC_RELAXED, __HIP_MEMORY_SCOPE_AGENT);
}
__device__ __forceinline__ void flag_store(int* p, int v) {
    __hip_atomic_store(p, v, __ATOMIC_RELAXED, __HIP_MEMORY_SCOPE_AGENT);
}
__device__ __forceinline__ u64  panel_load(const u64* p) {
    return __hip_atomic_load(p, __ATOMIC_RELAXED, __HIP_MEMORY_SCOPE_AGENT);
}
__device__ __forceinline__ void panel_store(u64* p, u64 v) {
    __hip_atomic_store(p, v, __ATOMIC_RELAXED, __HIP_MEMORY_SCOPE_AGENT);
}

__device__ __forceinline__ void cvt_store4(f16* dst, f32x4 v) {
    f16x4 h;
    h[0] = (f16)v[0]; h[1] = (f16)v[1]; h[2] = (f16)v[2]; h[3] = (f16)v[3];
    *reinterpret_cast<f16x4*>(dst) = h;
}

// Persistent per-wave LSTM state for one 16-col u-tile (all 4 gates).
// Weights scaled by log2e (gates i,f,o) and 2*log2e (gate g) at load time;
// cell state kept in the 2*log2e domain. Gate nonlinearities use merged-rcp
// forms: sigma(i)*tanh(g) = 2L2E*(G-1)/((1+Ei)(G+1)), h = (C-1)/((1+Eo)(C+1))
// -> 8 trans per acc row instead of 10, one less serial trans level.
template <int IN_DIM, int H>
struct Lstm {
    static constexpr int KTX = IN_DIM / 32, KTH = H / 32, KT = KTX + KTH;
    f16x8 bw[4][KT];
    float bias[4];
    float cst[4];
    int u, q;

    __device__ __forceinline__ void init(const float* __restrict__ w_ih,
                                         const float* __restrict__ w_hh,
                                         const float* __restrict__ b_ih,
                                         const float* __restrict__ b_hh,
                                         int unit, int lane) {
        q = lane >> 4;
        u = unit * 16 + (lane & 15);
#pragma unroll
        for (int g = 0; g < 4; ++g) {
            const float sc = (g == 2) ? 2.0f * L2E : L2E;
            const int row = g * H + u;
#pragma unroll
            for (int kt = 0; kt < KTX; ++kt) {
                const float* p = w_ih + (size_t)row * IN_DIM + kt * 32 + q * 8;
                f16x8 v;
#pragma unroll
                for (int j = 0; j < 8; ++j) v[j] = (f16)(p[j] * sc);
                bw[g][kt] = v;
            }
#pragma unroll
            for (int kt = 0; kt < KTH; ++kt) {
                const float* p = w_hh + (size_t)row * H + kt * 32 + q * 8;
                f16x8 v;
#pragma unroll
                for (int j = 0; j < 8; ++j) v[j] = (f16)(p[j] * sc);
                bw[g][KTX + kt] = v;
            }
            bias[g] = (b_ih[g * H + u] + b_hh[g * H + u]) * sc;
            cst[g] = 0.f;
        }
    }

    // in_row  = &input[ip][col][0]  (f16, row stride = input pad width)
    // rec_row = &own_h[wp^1][col][0]
    // hdst    = &own_h[wp][0][0] ; writes hdst[(4q+r)*hp + u]
    __device__ __forceinline__ void step(const f16* in_row, const f16* rec_row,
                                         f16* hdst, int hp, float hold[4]) {
        f16x8 a[KT];
#pragma unroll
        for (int kt = 0; kt < KTX; ++kt)
            a[kt] = *reinterpret_cast<const f16x8*>(in_row + kt * 32 + q * 8);
#pragma unroll
        for (int kt = 0; kt < KTH; ++kt)
            a[KTX + kt] = *reinterpret_cast<const f16x8*>(rec_row + kt * 32 + q * 8);
        f32x4 acc[4];
#pragma unroll
        for (int g = 0; g < 4; ++g)
            acc[g] = (f32x4){bias[g], bias[g], bias[g], bias[g]};
        __builtin_amdgcn_s_setprio(1);
#pragma unroll
        for (int kt = 0; kt < KT; ++kt)
#pragma unroll
            for (int g = 0; g < 4; ++g)
                acc[g] = __builtin_amdgcn_mfma_f32_16x16x32_f16(a[kt], bw[g][kt], acc[g], 0, 0, 0);
#pragma unroll
        for (int r = 0; r < 4; ++r) {
            const float yi = acc[0][r], yf = acc[1][r], yg = acc[2][r], yo = acc[3][r];
            const float Ei = exp2_f(-yi);
            const float G  = exp2_f(yg);                 // e^{2g}
            const float Ef = exp2_f(-yf);
            const float sf = rcp_f(1.0f + Ef);
            const float itg = (2.0f * L2E) * (G - 1.0f) *
                              rcp_f((1.0f + Ei) * (G + 1.0f));   // si * 2L2E*tanh(g)
            cst[r] = fmaf(sf, cst[r], itg);              // c' in 2L2E domain
            const float C  = exp2_f(cst[r]);             // e^{2c'}
            const float Eo = exp2_f(-yo);
            const float h  = (C - 1.0f) * rcp_f((1.0f + Eo) * (C + 1.0f)); // so*tanh(c')
            hdst[(4 * q + r) * hp + u] = (f16)h;
            hold[r] = h;
        }
        __builtin_amdgcn_s_setprio(0);
    }
};

// Pair-fused pipeline:
//   blocks 0..15  (A): L1 (64->128, waves 0-7) + L2 (128->32, waves 8-9) +
//                      X-stagers (waves 10-11, 2-step-deep). L1->L2 in LDS.
//                      L2 publishes tanh'd 32-wide panels with COUNTED drain
//                      (vmcnt(2), flag = ss-3) so the drain never blocks.
//   blocks 16..31 (B): L3 (32->128, waves 0-7; wave 0 stages h2 panels with
//                      2-step-deep prefetch + per-step non-blocking flag
//                      refresh) + L4 (128->64, waves 8-11, fp32 out).
// At global step s: L1 computes t=s, L2 t=s-1 (block A); L3 t=s, L4 t=s-1.
__global__ __launch_bounds__(768, 3)
void lstm_fused(const float* __restrict__ X,
                const float* __restrict__ w1_ih, const float* __restrict__ w1_hh,
                const float* __restrict__ b1_ih, const float* __restrict__ b1_hh,
                const float* __restrict__ w2_ih, const float* __restrict__ w2_hh,
                const float* __restrict__ b2_ih, const float* __restrict__ b2_hh,
                const float* __restrict__ w3_ih, const float* __restrict__ w3_hh,
                const float* __restrict__ b3_ih, const float* __restrict__ b3_hh,
                const float* __restrict__ w4_ih, const float* __restrict__ w4_hh,
                const float* __restrict__ b4_ih, const float* __restrict__ b4_hh,
                f16* __restrict__ h2t, int* __restrict__ flags,
                float* __restrict__ out)
{
    __shared__ __attribute__((aligned(16))) char sm[16384];
    const int b = blockIdx.x, tid = threadIdx.x;
    const int wave = tid >> 6, lane = tid & 63;
    const int col = lane & 15;

    if (b < 16) {
        // ================= block A: L1 + L2 =================
        const int g = b, bblk = g * 16;
        int* out_flag = flags + g;
        constexpr int XP1 = 72, HP1 = 136, HP2 = 40;            // padded row widths
        constexpr int XS_P = 16 * XP1, H1_P = 16 * HP1, H2_P = 16 * HP2;
        f16* xs  = (f16*)sm;                 // [2][16][72]   4608 B
        f16* h1  = (f16*)(sm + 4608);        // [2][16][136]  8704 B
        f16* h2r = (f16*)(sm + 13312);       // [2][16][40]   2560 B (raw h2, recurrence)

        // zero h1 + h2r (contiguous region)
        for (int i = tid; i < (2 * H1_P + 2 * H2_P) / 2; i += 768)
            ((u32*)h1)[i] = 0u;

        // stager setup (waves 10-11): 2 f32x4 chunks/lane, 2-step-deep prefetch.
        // x(k) odd -> set A, even -> set B.
        const float* xg0 = nullptr; const float* xg1 = nullptr;
        f16* xl0 = nullptr; f16* xl1 = nullptr;
        f32x4 hvA0{}, hvA1{}, hvB0{}, hvB1{};
        if (wave >= 10) {
            const int c0 = tid - 640, c1 = c0 + 128;
            const int r0 = c0 >> 4, o0 = (c0 & 15) * 4;
            const int r1 = c1 >> 4, o1 = (c1 & 15) * 4;
            xg0 = X + (size_t)(bblk + r0) * 64 + o0;
            xg1 = X + (size_t)(bblk + r1) * 64 + o1;
            xl0 = xs + r0 * XP1 + o0;
            xl1 = xs + r1 * XP1 + o1;
            // x(0) -> xs[0] direct
            f32x4 v0 = *(const f32x4*)xg0, v1 = *(const f32x4*)xg1;
            cvt_store4(xl0, v0); cvt_store4(xl1, v1);
            xg0 += (size_t)BATCH * 64; xg1 += (size_t)BATCH * 64;
            // issue x(1) -> set A
            hvA0 = *(const f32x4*)xg0; hvA1 = *(const f32x4*)xg1;
            xg0 += (size_t)BATCH * 64; xg1 += (size_t)BATCH * 64;
            // issue x(2) -> set B
            hvB0 = *(const f32x4*)xg0; hvB1 = *(const f32x4*)xg1;
            xg0 += (size_t)BATCH * 64; xg1 += (size_t)BATCH * 64;
        }
        barrier_lgkm();   // zeroes + x(0) visible (prefetches stay in flight)

        if (wave < 8) {
            // ---- L1: 64 -> 128, t = s ----
            Lstm<64, 128> L;
            L.init(w1_ih, w1_hh, b1_ih, b1_hh, wave, lane);
            float hd[4];
            const f16* in0 = xs + col * XP1;
            const f16* in1 = xs + XS_P + col * XP1;
            const f16* rc0 = h1 + col * HP1;
            const f16* rc1 = h1 + H1_P + col * HP1;
            f16* d0 = h1;
            f16* d1 = h1 + H1_P;
            for (int ss = 0; ss < 512; ss += 2) {
                L.step(in0, rc1, d0, HP1, hd);   // s=ss   (wp=0)
                barrier_lgkm();
                L.step(in1, rc0, d1, HP1, hd);   // s=ss+1 (wp=1)
                barrier_lgkm();
            }
            barrier_lgkm();   // tail s=512 (inactive)
            barrier_lgkm();   // post (final panel/flag sync)
        } else if (wave < 10) {
            // ---- L2: 128 -> 32, t2 = s-1; tanh'd panel -> global ----
            Lstm<128, 32> L;
            L.init(w2_ih, w2_hh, b2_ih, b2_hh, wave - 8, lane);
            float hd[4];
            const int t2id = tid - 512, orow = t2id >> 3, ooff = t2id & 7;
            u64* opg = (u64*)(h2t + (size_t)(bblk + orow) * 32) + ooff;
            const f16* in0 = h1 + col * HP1;               // ip == wp for delay-1 input
            const f16* in1 = h1 + H1_P + col * HP1;
            const f16* rc0 = h2r + col * HP2;
            const f16* rc1 = h2r + H2_P + col * HP2;
            f16* d0 = h2r;
            f16* d1 = h2r + H2_P;
            const f16* ol0 = h2r + orow * HP2 + ooff * 4;          // panel src parity 0
            const f16* ol1 = h2r + H2_P + orow * HP2 + ooff * 4;   // panel src parity 1
            for (int ss = 0; ss < 512; ss += 2) {
                // subA: s=ss, t2=ss-1 (odd, wp=1); active iff ss>=2
                if (ss >= 2) {
                    panel_store(opg, tanh4_f16(*(const u64*)ol0));  // panel ss-2 (even)
                    opg += (size_t)BATCH * 32 / 4;
                    L.step(in1, rc0, d1, HP2, hd);
                }
                // counted drain: leaves {panel ss-3, ss-2} in flight, guarantees
                // panels <= ss-4 complete. Never waits on a fresh store.
                if (ss >= 4 && (ss & 3) == 0) wait_vm2();
                barrier_lgkm();
                // subB: s=ss+1, t2=ss (even, wp=0)
                if (ss >= 4 && (ss & 3) == 0 && t2id == 0)
                    flag_store(out_flag, ss - 3);   // panels 0..ss-4 visible
                if (ss >= 2) {
                    panel_store(opg, tanh4_f16(*(const u64*)ol1));  // panel ss-1 (odd)
                    opg += (size_t)BATCH * 32 / 4;
                }
                L.step(in0, rc1, d0, HP2, hd);
                barrier_lgkm();
            }
            // tail s=512: t2=511 (wp=1); store panel 510
            panel_store(opg, tanh4_f16(*(const u64*)ol0));
            opg += (size_t)BATCH * 32 / 4;
            L.step(in1, rc0, d1, HP2, hd);
            barrier_lgkm();
            // post: final panel 511, full drain, publish final flag
            panel_store(opg, tanh4_f16(*(const u64*)ol1));
            barrier_drain();
            if (t2id == 0) flag_store(out_flag, T_STEPS + 8);
        } else {
            // ---- X stagers: commit x(s+1) (2 steps in flight), issue x(s+3) ----
            for (int ss = 0; ss < 512; ss += 2) {
                // subA (t=ss): commit x(ss+1) -> xs[1] (set A, odd)
                cvt_store4(xl0 + XS_P, hvA0); cvt_store4(xl1 + XS_P, hvA1);
                if (ss + 3 < 512) {
                    hvA0 = *(const f32x4*)xg0; hvA1 = *(const f32x4*)xg1;
                    xg0 += (size_t)BATCH * 64; xg1 += (size_t)BATCH * 64;
                }
                barrier_lgkm();
                // subB (t=ss+1): commit x(ss+2) -> xs[0] (set B, even)
                if (ss + 2 < 512) { cvt_store4(xl0, hvB0); cvt_store4(xl1, hvB1); }
                if (ss + 4 < 512) {
                    hvB0 = *(const f32x4*)xg0; hvB1 = *(const f32x4*)xg1;
                    xg0 += (size_t)BATCH * 64; xg1 += (size_t)BATCH * 64;
                }
                barrier_lgkm();
            }
            barrier_lgkm();
            barrier_lgkm();
        }
    } else {
        // ================= block B: L3 + L4 =================
        const int g = b - 16, bblk = g * 16;
        const int* in_flag = flags + g;
        constexpr int XP3 = 40, HP3 = 136, HP4 = 72;
        constexpr int X3_P = 16 * XP3, H3_P = 16 * HP3, H4_P = 16 * HP4;
        f16* xs3 = (f16*)sm;                 // [2][16][40]   2560 B
        f16* h3  = (f16*)(sm + 2560);        // [2][16][136]  8704 B
        f16* h4  = (f16*)(sm + 11264);       // [2][16][72]   4608 B

        for (int i = tid; i < (2 * H3_P + 2 * H4_P) / 2; i += 768)
            ((u32*)h3)[i] = 0u;

        // stager = wave 0: one f16x8 chunk each (64 chunks), 2-step-deep.
        // x(k) odd -> set A, even -> set B. flp = per-step prefetched flag.
        const char* sgp = nullptr; f16* slp = nullptr;
        u64 hA0 = 0, hA1 = 0, hB0 = 0, hB1 = 0;
        int seen = 0, flp = 0;
        if (wave == 0) {
            const int r_ = tid >> 2, o_ = (tid & 3) * 8;
            sgp = (const char*)h2t + ((size_t)(bblk + r_) * 32 + o_) * 2;
            slp = xs3 + r_ * XP3 + o_;
            do { seen = flag_load(in_flag); } while (seen < 1);
            u64 pk[2];
            pk[0] = panel_load((const u64*)sgp);
            pk[1] = panel_load((const u64*)sgp + 1);
            sgp += (size_t)BATCH * 64;
            *reinterpret_cast<f16x8*>(slp) = *reinterpret_cast<const f16x8*>(pk);  // x(0)->xs3[0]
            while (seen < 2) seen = flag_load(in_flag);
            hA0 = panel_load((const u64*)sgp);   // issue x(1) -> set A
            hA1 = panel_load((const u64*)sgp + 1);
            sgp += (size_t)BATCH * 64;
            while (seen < 3) seen = flag_load(in_flag);
            hB0 = panel_load((const u64*)sgp);   // issue x(2) -> set B
            hB1 = panel_load((const u64*)sgp + 1);
            sgp += (size_t)BATCH * 64;
            flp = seen;
        }
        barrier_lgkm();

        if (wave < 8) {
            // ---- L3: 32 -> 128, t = s; wave 0 also stages h2 panels ----
            Lstm<32, 128> L;
            L.init(w3_ih, w3_hh, b3_ih, b3_hh, wave, lane);
            float hd[4];
            const f16* in0 = xs3 + col * XP3;
            const f16* in1 = xs3 + X3_P + col * XP3;
            const f16* rc0 = h3 + col * HP3;
            const f16* rc1 = h3 + H3_P + col * HP3;
            f16* d0 = h3;
            f16* d1 = h3 + H3_P;
            for (int ss = 0; ss < 512; ss += 2) {
                // s=ss (wp=0): commit x(ss+1) (set A); issue x(ss+3)
                if (wave == 0) {
                    u64 pk[2] = {hA0, hA1};
                    *reinterpret_cast<f16x8*>(slp + X3_P) = *reinterpret_cast<const f16x8*>(pk);
                    if (ss + 3 < 512) {
                        if (flp > seen) seen = flp;
                        while (seen < ss + 4) seen = flag_load(in_flag);
                        hA0 = panel_load((const u64*)sgp);
                        hA1 = panel_load((const u64*)sgp + 1);
                        sgp += (size_t)BATCH * 64;
                    }
                    flp = flag_load(in_flag);   // non-blocking until next use
                }
                L.step(in0, rc1, d0, HP3, hd);
                barrier_lgkm();
                // s=ss+1 (wp=1): commit x(ss+2) (set B); issue x(ss+4)
                if (wave == 0) {
                    if (ss + 2 < 512) {
                        u64 pk[2] = {hB0, hB1};
                        *reinterpret_cast<f16x8*>(slp) = *reinterpret_cast<const f16x8*>(pk);
                    }
                    if (ss + 4 < 512) {
                        if (flp > seen) seen = flp;
                        while (seen < ss + 5) seen = flag_load(in_flag);
                        hB0 = panel_load((const u64*)sgp);
                        hB1 = panel_load((const u64*)sgp + 1);
                        sgp += (size_t)BATCH * 64;
                    }
                    flp = flag_load(in_flag);
                }
                L.step(in1, rc0, d1, HP3, hd);
                barrier_lgkm();
            }
            barrier_lgkm();   // tail s=512 (inactive)
        } else {
            // ---- L4: 128 -> 64, t4 = s-1, fp32 delayed out-writes ----
            Lstm<128, 64> L;
            L.init(w4_ih, w4_hh, b4_ih, b4_hh, wave - 8, lane);
            float hold[4] = {0.f, 0.f, 0.f, 0.f};
            const int q4 = lane >> 4;
            const int u4 = (wave - 8) * 16 + col;
            float* outp = out + ((size_t)bblk + 4 * q4) * 64 + u4;
            const f16* in0 = h3 + col * HP3;
            const f16* in1 = h3 + H3_P + col * HP3;
            const f16* rc0 = h4 + col * HP4;
            const f16* rc1 = h4 + H4_P + col * HP4;
            f16* d0 = h4;
            f16* d1 = h4 + H4_P;
            for (int ss = 0; ss < 512; ss += 2) {
                // subA: s=ss, t4=ss-1 (odd, wp=1); active iff ss>=2
                if (ss >= 2) {
#pragma unroll
                    for (int r = 0; r < 4; ++r) outp[r * 64] = hold[r];  // out(t4-1)
                    outp += (size_t)BATCH * 64;
                    L.step(in1, rc0, d1, HP4, hold);
                }
                barrier_lgkm();
                // subB: s=ss+1, t4=ss (even, wp=0)
                if (ss >= 2) {
#pragma unroll
                    for (int r = 0; r < 4; ++r) outp[r * 64] = hold[r];
                    outp += (size_t)BATCH * 64;
                }
                L.step(in0, rc1, d0, HP4, hold);
                barrier_lgkm();
            }
            // tail s=512: t4=511 (wp=1)
#pragma unroll
            for (int r = 0; r < 4; ++r) outp[r * 64] = hold[r];   // out(510)
            outp += (size_t)BATCH * 64;
            L.step(in1, rc0, d1, HP4, hold);
            barrier_lgkm();
            // epilogue: out(511)
#pragma unroll
            for (int r = 0; r < 4; ++r) outp[r * 64] = hold[r];
        }
    }
}

extern "C" void kernel_launch(void* const* d_in, const int* in_sizes, int n_in,
                              void* d_out, int out_size, void* d_ws, size_t ws_size,
                              hipStream_t stream) {
    const float* X     = (const float*)d_in[0];
    const float* w1_ih = (const float*)d_in[1];
    const float* w1_hh = (const float*)d_in[2];
    const float* b1_ih = (const float*)d_in[3];
    const float* b1_hh = (const float*)d_in[4];
    const float* w2_ih = (const float*)d_in[5];
    const float* w2_hh = (const float*)d_in[6];
    const float* b2_ih = (const float*)d_in[7];
    const float* b2_hh = (const float*)d_in[8];
    const float* w3_ih = (const float*)d_in[9];
    const float* w3_hh = (const float*)d_in[10];
    const float* b3_ih = (const float*)d_in[11];
    const float* b3_hh = (const float*)d_in[12];
    const float* w4_ih = (const float*)d_in[13];
    const float* w4_hh = (const float*)d_in[14];
    const float* b4_ih = (const float*)d_in[15];
    const float* b4_hh = (const float*)d_in[16];

    float* out = (float*)d_out;

    // ws: flags[16] ints (poison 0xAAAAAAAA < 0 => "not ready"), then the one
    // remaining inter-block panel: h2t = tanh(h2), f16 [T,B,32] (8 MB).
    int* flags = (int*)d_ws;
    f16* h2t = (f16*)((char*)d_ws + 256);

    lstm_fused<<<32, 768, 0, stream>>>(X,
        w1_ih, w1_hh, b1_ih, b1_hh, w2_ih, w2_hh, b2_ih, b2_hh,
        w3_ih, w3_hh, b3_ih, b3_hh, w4_ih, w4_hh, b4_ih, b4_hh,
        h2t, flags, out);
}